// Round 5
// baseline (69.857 us; speedup 1.0000x reference)
//
#include <hip/hip_runtime.h>

#define BN   8192
#define DIM  128
#define NCLS 128
#define NBLK 512          // 128 i-tiles x 4 j-splits
#define NS   32           // stages per block: 2048 j / 64

typedef __attribute__((ext_vector_type(8))) short bf16x8;   // 8 x bf16 = 4 VGPRs
typedef __attribute__((ext_vector_type(4))) float f32x4;

// round-to-nearest-even f32 -> bf16
static __device__ __forceinline__ unsigned short f2bf(float x) {
    union { float f; unsigned u; } c; c.f = x;
    unsigned r = c.u + 0x7FFFu + ((c.u >> 16) & 1u);
    return (unsigned short)(r >> 16);
}

static __device__ __forceinline__ bf16x8 ldb8(const unsigned short* p) {
    return *reinterpret_cast<const bf16x8*>(p);
}

// monotone float<->uint key: enc(a) < enc(b)  <=>  a < b
static __device__ __forceinline__ unsigned encf(float f) {
    unsigned u = __float_as_uint(f);
    return (u >> 31) ? ~u : (u | 0x80000000u);
}
static __device__ __forceinline__ float decf(unsigned v) {
    return __uint_as_float((v >> 31) ? (v & 0x7FFFFFFFu) : ~v);
}

// async global->LDS, 16B/lane; LDS dest wave-uniform base + lane*16
static __device__ __forceinline__ void gload_lds16(const unsigned short* g, unsigned short* l) {
    __builtin_amdgcn_global_load_lds(
        (const __attribute__((address_space(1))) unsigned int*)g,
        (__attribute__((address_space(3))) unsigned int*)l, 16, 0, 0);
}

// ---------------- S1: fused sort (block-per-class) + normalize + init -------
// Block c: counts labels<c (class offset) and collects its rows in a fixed
// deterministic order (thread-major, then iteration order), then normalizes
// and scatters bf16 rows into sorted positions. Also resets the done counter.
__global__ __launch_bounds__(256) void sort_norm(const float* __restrict__ emb,
                                                 const int* __restrict__ labels,
                                                 unsigned short* __restrict__ ebf,
                                                 int2* __restrict__ se,
                                                 unsigned* __restrict__ hp2,
                                                 unsigned* __restrict__ hn2,
                                                 int* __restrict__ done) {
    const int c   = blockIdx.x;              // class id
    const int tid = threadIdx.x;
    if (c == 0 && tid == 0) *done = 0;       // reset last-block counter each call
    __shared__ int sl[256], so[256];
    __shared__ int srcrow[512];              // class size guard (E=64, sd~8)

    int nl = 0, no = 0;
#pragma unroll 8
    for (int k = 0; k < 32; ++k) {           // coalesced label reads
        int lb = labels[k * 256 + tid];
        nl += (lb < c);
        no += (lb == c);
    }
    sl[tid] = nl; so[tid] = no;
    __syncthreads();
    for (int off = 1; off < 256; off <<= 1) {   // Hillis-Steele inclusive scan
        int a1 = 0, a2 = 0;
        if (tid >= off) { a1 = sl[tid - off]; a2 = so[tid - off]; }
        __syncthreads();
        sl[tid] += a1; so[tid] += a2;
        __syncthreads();
    }
    const int offs_c = sl[255];              // rows with label < c
    const int n_c    = so[255];              // class size
    int mypos = so[tid] - no;                // exclusive prefix of own-count
    for (int k = 0; k < 32; ++k) {           // deterministic placement
        int r = k * 256 + tid;
        if (labels[r] == c) srcrow[mypos++] = r;
    }
    __syncthreads();

    const int wave = tid >> 6, lane = tid & 63;
    for (int k = wave; k < n_c; k += 4) {
        int r   = srcrow[k];
        int pos = offs_c + k;
        float2 v = reinterpret_cast<const float2*>(emb + (size_t)r * DIM)[lane];
        float ss = v.x * v.x + v.y * v.y;
#pragma unroll
        for (int m = 1; m < 64; m <<= 1) ss += __shfl_xor(ss, m);
        float inv = 1.0f / fmaxf(sqrtf(ss), 1e-12f);
        ushort2 bv; bv.x = f2bf(v.x * inv); bv.y = f2bf(v.y * inv);
        reinterpret_cast<ushort2*>(ebf + (size_t)pos * DIM)[lane] = bv;
        if (lane == 0) {
            se[pos]  = make_int2(offs_c, offs_c + n_c);
            hp2[pos] = 0xFFFFFFFFu;          // min-key identity
            hn2[pos] = 0u;                   // max-key identity
        }
    }
}

// --------------------------------- main -------------------------------------
// 512 blocks = 128 i-tiles (64 sorted rows) x 4 j-splits; 4 waves; 32 stages
// of 64 j-cols. B triple-buffered in LDS via global_load_lds, depth-2
// prefetch with COUNTED vmcnt (never drained to 0 in the loop) + raw
// s_barrier (T3/T4), setprio around the MFMA cluster (T5).
// Tracks DOT products: hardest_pos = min dot over same-class (self included,
// self-dot~1 never the min), hardest_neg = max dot over rest.
// Last block to finish folds the finalize reduction (done-counter handshake).
__global__ __launch_bounds__(256) void tri_main(const unsigned short* __restrict__ ebf,
                                                const int2* __restrict__ se,
                                                unsigned* __restrict__ hp2,
                                                unsigned* __restrict__ hn2,
                                                int* __restrict__ done,
                                                float* __restrict__ out) {
    __shared__ unsigned short bs[3][64 * DIM];   // 3 x 16 KiB B tiles
    __shared__ float hpL[4][64], hnL[4][64];
    __shared__ int amlast;

    const int tid  = threadIdx.x;
    const int wave = tid >> 6;
    const int lane = tid & 63;
    const int lr   = lane & 15;        // A row / B col / C col within 16x16 tile
    const int lk   = lane >> 4;        // k-group
    const int itile  = blockIdx.x >> 2;
    const int jsplit = blockIdx.x & 3;
    const int i0    = itile * 64;
    const int jbase = jsplit * 2048;

    // A panel: 4 x 16-row subtiles, K=128 (one-time, L2-hit)
    bf16x8 a[4][4];
#pragma unroll
    for (int t = 0; t < 4; ++t) {
        const unsigned short* ar = ebf + (size_t)(i0 + t * 16 + lr) * DIM + lk * 8;
#pragma unroll
        for (int kk = 0; kk < 4; ++kk) a[t][kk] = ldb8(ar + kk * 32);
    }

    // block window: union of class ranges of rows i0..i0+63 (sorted => contiguous)
    const int w0 = __builtin_amdgcn_readfirstlane(se[i0].x);
    const int w1 = __builtin_amdgcn_readfirstlane(se[i0 + 63].y);

    // per-acc-row class range, packed (start<<16 | len)
    int sepk[4][4];
#pragma unroll
    for (int t = 0; t < 4; ++t)
#pragma unroll
        for (int m = 0; m < 4; ++m) {
            int2 q = se[i0 + t * 16 + lk * 4 + m];
            sepk[t][m] = (q.x << 16) | (q.y - q.x);
        }

    float hp[4][4], hn[4][4];                // dot-space: min-pos / max-neg
#pragma unroll
    for (int t = 0; t < 4; ++t)
#pragma unroll
        for (int m = 0; m < 4; ++m) { hp[t][m] = 1e30f; hn[t][m] = -1e30f; }

    // ds_read byte offsets within a buffer (both-sides XOR swizzle), per lane
    int rdoff[4];
    {
        const int rowb = wave * 16 + lr;
#pragma unroll
        for (int kk = 0; kk < 4; ++kk)
            rdoff[kk] = rowb * 256 + (((((kk << 2) | lk)) ^ (lr & 7)) << 4);
    }

    // staging: wave w stages rows [w*16, w*16+16) of the 64-row j-tile (4 instrs)
    const int srow16 = lane >> 4;
    const int schk   = lane & 15;
    auto STAGE = [&](int buf, int s) {
        const unsigned short* gb = ebf + (size_t)(jbase + s * 64 + wave * 16) * DIM;
#pragma unroll
        for (int l = 0; l < 4; ++l) {
            int r4 = l * 4 + srow16;
            const unsigned short* g = gb + (size_t)r4 * DIM + ((schk ^ (r4 & 7)) << 3);
            gload_lds16(g, &bs[buf][(wave * 16 + l * 4) * DIM]);
        }
    };

    STAGE(0, 0);
    STAGE(1, 1);

    int cur = 0;
    for (int s = 0; s < NS; ++s) {
        // counted wait: stage-s loads (oldest) complete; stage-s+1's 4 stay in flight
        if (s == NS - 1) { asm volatile("s_waitcnt vmcnt(0)" ::: "memory"); }
        else             { asm volatile("s_waitcnt vmcnt(4)" ::: "memory"); }
        __builtin_amdgcn_s_barrier();
        __builtin_amdgcn_sched_barrier(0);

        if (s + 2 < NS) {                    // depth-2 prefetch into buf (cur+2)%3
            int sb = cur + 2; if (sb >= 3) sb -= 3;
            STAGE(sb, s + 2);
        }

        const char* bb = reinterpret_cast<const char*>(&bs[cur][0]);
        bf16x8 b0 = *reinterpret_cast<const bf16x8*>(bb + rdoff[0]);
        bf16x8 b1 = *reinterpret_cast<const bf16x8*>(bb + rdoff[1]);
        bf16x8 b2 = *reinterpret_cast<const bf16x8*>(bb + rdoff[2]);
        bf16x8 b3 = *reinterpret_cast<const bf16x8*>(bb + rdoff[3]);

        f32x4 acc[4];
        __builtin_amdgcn_s_setprio(1);
#pragma unroll
        for (int t = 0; t < 4; ++t) {
            f32x4 c4 = {0.f, 0.f, 0.f, 0.f};
            c4 = __builtin_amdgcn_mfma_f32_16x16x32_bf16(a[t][0], b0, c4, 0, 0, 0);
            c4 = __builtin_amdgcn_mfma_f32_16x16x32_bf16(a[t][1], b1, c4, 0, 0, 0);
            c4 = __builtin_amdgcn_mfma_f32_16x16x32_bf16(a[t][2], b2, c4, 0, 0, 0);
            c4 = __builtin_amdgcn_mfma_f32_16x16x32_bf16(a[t][3], b3, c4, 0, 0, 0);
            acc[t] = c4;
        }
        __builtin_amdgcn_s_setprio(0);

        const int j0w = jbase + s * 64 + wave * 16;        // this wave's 16 cols
        if (j0w + 16 <= w0 || j0w >= w1) {                 // pure-negative (common)
#pragma unroll
            for (int t = 0; t < 4; ++t)
#pragma unroll
                for (int m = 0; m < 4; ++m) hn[t][m] = fmaxf(hn[t][m], acc[t][m]);
        } else {                                           // mixed (near diagonal)
            const int jc = j0w + lr;
#pragma unroll
            for (int t = 0; t < 4; ++t)
#pragma unroll
                for (int m = 0; m < 4; ++m) {
                    int  st  = sepk[t][m] >> 16;
                    int  len = sepk[t][m] & 0xFFFF;
                    bool pos = (unsigned)(jc - st) < (unsigned)len;
                    hp[t][m] = pos ? fminf(hp[t][m], acc[t][m]) : hp[t][m];
                    hn[t][m] = pos ? hn[t][m] : fmaxf(hn[t][m], acc[t][m]);
                }
        }
        cur = (cur == 2) ? 0 : cur + 1;
    }

    // reduce across the 16 lanes sharing accum rows, then across waves in LDS
#pragma unroll
    for (int t = 0; t < 4; ++t)
#pragma unroll
        for (int m = 0; m < 4; ++m) {
            float p = hp[t][m], n = hn[t][m];
#pragma unroll
            for (int sft = 1; sft < 16; sft <<= 1) {
                p = fminf(p, __shfl_xor(p, sft));
                n = fmaxf(n, __shfl_xor(n, sft));
            }
            if (lr == 0) {
                int r = t * 16 + lk * 4 + m;
                hpL[wave][r] = p;
                hnL[wave][r] = n;
            }
        }
    __syncthreads();
    if (tid < 64) {
        float p = fminf(fminf(hpL[0][tid], hpL[1][tid]), fminf(hpL[2][tid], hpL[3][tid]));
        float n = fmaxf(fmaxf(hnL[0][tid], hnL[1][tid]), fmaxf(hnL[2][tid], hnL[3][tid]));
        atomicMin(&hp2[i0 + tid], encf(p));
        atomicMax(&hn2[i0 + tid], encf(n));
    }
    __syncthreads();                         // all this block's atomics performed

    // ---- folded finalize: last block to arrive reduces hp2/hn2 -> out[0] ----
    if (tid == 0) {
        __threadfence();                     // release our atomics
        amlast = (atomicAdd(done, 1) == NBLK - 1);
    }
    __syncthreads();
    if (!amlast) return;
    __threadfence();                         // acquire all blocks' atomics

    float sum = 0.f;
#pragma unroll
    for (int it = 0; it < BN / 256; ++it) {
        int i = it * 256 + tid;
        float pd = decf(hp2[i]);             // min dot over pos
        float nd = decf(hn2[i]);             // max dot over neg
        float hpv = sqrtf(fmaxf(2.0f - 2.0f * pd, 0.f));
        float hnv = sqrtf(fmaxf(2.0f - 2.0f * nd, 0.f));
        // relu(hp - hn + 0.5*(1+hp)) = relu(1.5*hp + 0.5 - hn)
        sum += fmaxf(fmaf(1.5f, hpv, 0.5f) - hnv, 0.f);
    }
    float* red = &hpL[0][0];                 // reuse 256 floats of LDS
    red[tid] = sum;
    __syncthreads();
    for (int s2 = 128; s2 > 0; s2 >>= 1) {
        if (tid < s2) red[tid] += red[tid + s2];
        __syncthreads();
    }
    if (tid == 0) out[0] = red[0] * (1.0f / (float)BN);    // all rows valid
}

// ---------------------------------------------------------------- launch
extern "C" void kernel_launch(void* const* d_in, const int* in_sizes, int n_in,
                              void* d_out, int out_size, void* d_ws, size_t ws_size,
                              hipStream_t stream) {
    const float* emb    = (const float*)d_in[0];
    const int*   labels = (const int*)d_in[1];
    float* out = (float*)d_out;

    char* ws = (char*)d_ws;
    unsigned short* ebf = (unsigned short*)ws;                            // 2 MiB sorted bf16 E
    int2*     se   = (int2*)    (ws + 2u * 1024u * 1024u);                // 64 KiB class ranges
    unsigned* hp2  = (unsigned*)(ws + 2u * 1024u * 1024u + 64u * 1024u);  // 32 KiB
    unsigned* hn2  = (unsigned*)(ws + 2u * 1024u * 1024u + 96u * 1024u);  // 32 KiB
    int*      done = (int*)     (ws + 2u * 1024u * 1024u + 128u * 1024u); // 4 B

    hipLaunchKernelGGL(sort_norm, dim3(NCLS), dim3(256), 0, stream, emb, labels, ebf, se, hp2, hn2, done);
    hipLaunchKernelGGL(tri_main,  dim3(NBLK), dim3(256), 0, stream, ebf, se, hp2, hn2, done, out);
}